// Round 1
// baseline (802.526 us; speedup 1.0000x reference)
//
#include <hip/hip_runtime.h>
#include <hip/hip_bf16.h>
#include <math.h>

#define NCELL 512          // 8^3 cells
#define IMG_F 16384        // NCELL * 32 floats = 64 KB

// ---------------------------------------------------------------------------
// K1: scatter points into per-block LDS lattices, write 64KB partial per block
// ---------------------------------------------------------------------------
__global__ __launch_bounds__(512) void k_scatter(
    const float* __restrict__ pos,
    const float* __restrict__ feat,
    float* __restrict__ partials,
    int n)
{
    __shared__ float lat[IMG_F];   // 64 KB
    const int t = threadIdx.x;
    for (int i = t; i < IMG_F; i += 512) lat[i] = 0.f;
    __syncthreads();

    const int c   = t & 31;        // channel lane
    const int sub = t >> 5;        // 0..15 point sub-slot
    const int chunk = (n + (int)gridDim.x - 1) / (int)gridDim.x;
    const int start = blockIdx.x * chunk;
    const int end   = min(start + chunk, n);

    for (int p = start + sub; p < end; p += 16) {
        const float px = pos[3*p+0], py = pos[3*p+1], pz = pos[3*p+2];
        const float v  = feat[(size_t)p*32 + c];
        const float sx = px*8.f, sy = py*8.f, sz = pz*8.f;
        const float bx = floorf(sx), by = floorf(sy), bz = floorf(sz);
        const float fx = sx-bx, fy = sy-by, fz = sz-bz;
        const int ix = ((int)bx) & 7, iy = ((int)by) & 7, iz = ((int)bz) & 7;
        const int ix1 = (ix+1)&7, iy1 = (iy+1)&7, iz1 = (iz+1)&7;
        const float gx = 1.f-fx, gy = 1.f-fy, gz = 1.f-fz;
        // float addrs: cell*32 + c ; strides: x:2048, y:256, z:32
        const int x0 = ix*2048,  x1 = ix1*2048;
        const int y0 = iy*256,   y1 = iy1*256;
        const int z0 = iz*32+c,  z1 = iz1*32+c;
        const float w00 = gx*gy*v, w01 = gx*fy*v, w10 = fx*gy*v, w11 = fx*fy*v;
        // bank = c for every lane-group -> 2-way aliasing only (free)
        unsafeAtomicAdd(&lat[x0+y0+z0], w00*gz);
        unsafeAtomicAdd(&lat[x0+y0+z1], w00*fz);
        unsafeAtomicAdd(&lat[x0+y1+z0], w01*gz);
        unsafeAtomicAdd(&lat[x0+y1+z1], w01*fz);
        unsafeAtomicAdd(&lat[x1+y0+z0], w10*gz);
        unsafeAtomicAdd(&lat[x1+y0+z1], w10*fz);
        unsafeAtomicAdd(&lat[x1+y1+z0], w11*gz);
        unsafeAtomicAdd(&lat[x1+y1+z1], w11*fz);
    }
    __syncthreads();
    float4* __restrict__ dst = (float4*)(partials + (size_t)blockIdx.x * IMG_F);
    const float4* __restrict__ src = (const float4*)lat;
    for (int i = t; i < IMG_F/4; i += 512) dst[i] = src[i];
}

// ---------------------------------------------------------------------------
// K2: reduce 256 partials -> img.  128 blocks x 256 thr, no atomics.
// ---------------------------------------------------------------------------
__global__ __launch_bounds__(256) void k_reduce(
    const float* __restrict__ partials,
    float* __restrict__ img)
{
    __shared__ float4 red[8][32];
    const int t = threadIdx.x;
    const int col = t & 31;
    const int g   = t >> 5;                      // 0..7: each group sums 32 rows
    const int col4 = blockIdx.x * 32 + col;      // 0..4095 (float4 columns)
    const float4* src = (const float4*)partials;
    float4 s = {0.f,0.f,0.f,0.f};
    for (int j = 0; j < 32; j++) {
        float4 v = src[(size_t)(g*32 + j) * (IMG_F/4) + col4];
        s.x += v.x; s.y += v.y; s.z += v.z; s.w += v.w;
    }
    red[g][col] = s;
    __syncthreads();
    if (g == 0) {
        float4 tot = red[0][col];
        #pragma unroll
        for (int gg = 1; gg < 8; gg++) {
            float4 v = red[gg][col];
            tot.x += v.x; tot.y += v.y; tot.z += v.z; tot.w += v.w;
        }
        ((float4*)img)[col4] = tot;
    }
}

// ---------------------------------------------------------------------------
// K3/K4/K5: periodic 3x3x3 conv, DHWOI weights [3][3][3][32][32].
// ACT=0: out = conv(in).  ACT=1: out = in + silu(conv(in)).
// Block = 256 thr handles 8 cells (one (ix,iy) column) x 32 couts.
// LDS: lattice staged as lds[cell*36 + cin]  (stride-36 pad: conflict-free,
// 16B aligned). Grid = 64 blocks.
// ---------------------------------------------------------------------------
template<int ACT>
__global__ __launch_bounds__(256) void k_conv(
    const float* __restrict__ in_lat,
    const float* __restrict__ w,
    float* __restrict__ out_lat)
{
    __shared__ float lds[NCELL*36];   // 73728 B
    const int t = threadIdx.x;
    for (int i = t; i < IMG_F/4; i += 256) {
        float4 v = ((const float4*)in_lat)[i];
        const int cell = i >> 3, c4 = i & 7;
        *(float4*)&lds[cell*36 + c4*4] = v;
    }
    __syncthreads();

    const int cout = t >> 3;                 // 0..31
    const int iz   = t & 7;                  // 0..7
    const int ix   = blockIdx.x >> 3, iy = blockIdx.x & 7;

    float4 acc = {0.f,0.f,0.f,0.f};
    #pragma unroll
    for (int kd = 0; kd < 3; kd++) {
      const int nx = (ix + kd + 7) & 7;
      #pragma unroll
      for (int kh = 0; kh < 3; kh++) {
        const int ny = (iy + kh + 7) & 7;
        #pragma unroll
        for (int kw = 0; kw < 3; kw++) {
          const int nz = (iz + kw + 7) & 7;
          const float* lrow = &lds[(nx*64 + ny*8 + nz)*36];
          const float* wrow = &w[(((kd*3 + kh)*3 + kw)*32 + cout)*32];
          #pragma unroll
          for (int c4i = 0; c4i < 8; c4i++) {
            const float4 a = *(const float4*)(lrow + c4i*4);
            const float4 b = *(const float4*)(wrow + c4i*4);
            acc.x = fmaf(a.x, b.x, acc.x);
            acc.y = fmaf(a.y, b.y, acc.y);
            acc.z = fmaf(a.z, b.z, acc.z);
            acc.w = fmaf(a.w, b.w, acc.w);
          }
        }
      }
    }
    float s = (acc.x + acc.y) + (acc.z + acc.w);
    const int oidx = (ix*64 + iy*8 + iz)*32 + cout;
    if (ACT == 1) {
        const float r = in_lat[oidx];
        s = r + s / (1.f + expf(-s));    // r + silu(conv)
    }
    out_lat[oidx] = s;
}

// ---------------------------------------------------------------------------
// K6: agg[cell] = sum over 8 corner-offset cells of out_lat  (512x32)
// ---------------------------------------------------------------------------
__global__ __launch_bounds__(256) void k_agg(
    const float* __restrict__ out_lat, float* __restrict__ agg)
{
    const int tid = blockIdx.x*256 + threadIdx.x;   // 0..4095
    if (tid >= 4096) return;
    const int cell = tid >> 3, c4 = tid & 7;
    const int ix = cell >> 6, iy = (cell >> 3) & 7, iz = cell & 7;
    float4 s = {0.f,0.f,0.f,0.f};
    #pragma unroll
    for (int k = 0; k < 8; k++) {
        const int nx = (ix + ((k>>2)&1)) & 7;
        const int ny = (iy + ((k>>1)&1)) & 7;
        const int nz = (iz + (k&1)) & 7;
        const float4 v = ((const float4*)out_lat)[(nx*64 + ny*8 + nz)*8 + c4];
        s.x += v.x; s.y += v.y; s.z += v.z; s.w += v.w;
    }
    ((float4*)agg)[tid] = s;
}

// ---------------------------------------------------------------------------
// K7: gather — out[p] = agg[base_cell(p)]  (pure table lookup, coalesced)
// ---------------------------------------------------------------------------
__global__ __launch_bounds__(256) void k_gather(
    const float* __restrict__ pos,
    const float* __restrict__ agg,
    float* __restrict__ out,
    int n)
{
    const int tid = blockIdx.x*256 + threadIdx.x;   // over n*8
    const int p = tid >> 3, c4 = tid & 7;
    if (p >= n) return;
    const int ix = ((int)floorf(pos[3*p+0]*8.f)) & 7;
    const int iy = ((int)floorf(pos[3*p+1]*8.f)) & 7;
    const int iz = ((int)floorf(pos[3*p+2]*8.f)) & 7;
    ((float4*)out)[tid] = ((const float4*)agg)[(ix*64 + iy*8 + iz)*8 + c4];
}

// ---------------------------------------------------------------------------
extern "C" void kernel_launch(void* const* d_in, const int* in_sizes, int n_in,
                              void* d_out, int out_size, void* d_ws, size_t ws_size,
                              hipStream_t stream)
{
    const float* pos  = (const float*)d_in[0];   // [N,3]
    const float* feat = (const float*)d_in[1];   // [N,32]
    const float* wenc = (const float*)d_in[2];   // [3,3,3,32,32]
    const float* winn = (const float*)d_in[3];   // [1,3,3,3,32,32]
    const float* wdec = (const float*)d_in[4];   // [3,3,3,32,32]
    float* out = (float*)d_out;
    const int n = in_sizes[0] / 3;

    float* ws       = (float*)d_ws;
    float* partials = ws;                         // 256 * 16384 floats (16 MB)
    float* img      = partials + 256*(size_t)IMG_F;
    float* h1       = img  + IMG_F;
    float* h2       = h1   + IMG_F;
    float* olat     = h2   + IMG_F;
    float* aggb     = olat + IMG_F;

    k_scatter<<<256, 512, 0, stream>>>(pos, feat, partials, n);
    k_reduce <<<128, 256, 0, stream>>>(partials, img);
    k_conv<0><<<64, 256, 0, stream>>>(img, wenc, h1);
    k_conv<1><<<64, 256, 0, stream>>>(h1,  winn, h2);
    k_conv<0><<<64, 256, 0, stream>>>(h2,  wdec, olat);
    k_agg    <<<16, 256, 0, stream>>>(olat, aggb);
    const int gblocks = (n*8 + 255)/256;
    k_gather <<<gblocks, 256, 0, stream>>>(pos, aggb, out, n);
}